// Round 7
// baseline (157.257 us; speedup 1.0000x reference)
//
#include <hip/hip_runtime.h>

// SelfAttention: B=4, S=2048, D=1024, fp32 in/out. bf16 MFMA, fp32 accum.
// R6: proj chained 3 tiles/block (grid 64x4 = 256 blocks, NT_eff = 48) --
// flat (tile,kt) indexing keeps the R4 counted-vmcnt cadence seamless across
// tile seams; per-tile epilogue interleaves between phase groups. sc8/pv8
// unchanged (grids already exactly 256; NT=16/32).
//   proj: 128x256 GEOM1 8-phase, grid (64,4), 3 chained N-tiles per block
//   sc:   256x256 GEOM0 8-phase, grid (8,8,4), P~=exp(QK^T/32)+rowsums
//   pv:   128x256 GEOM1 8-phase, grid (16,4,4), * 1/rowsum (in-kernel rsum)
// ws layout (MiB):
//   [0,16)   x_bf16 (proj) -> P~ bf16 [4][2048][2048]
//   [16,32)  Q bf16   [32,48) K bf16   [48,64) Vt bf16 [4][1024][2048]
//   [64,70)  Wq|Wk|Wv bf16
//   [70,+256K) rowpart fp32 [8][4][2048]

typedef __bf16 bf16x8 __attribute__((ext_vector_type(8)));
typedef float f32x4 __attribute__((ext_vector_type(4)));
typedef unsigned short u16;

__device__ __forceinline__ u16 f2b(float f) {
  union { float f; unsigned u; } a; a.f = f;
  unsigned r = a.u + 0x7fffu + ((a.u >> 16) & 1u);  // RNE
  return (u16)(r >> 16);
}

// blocks [0,8192): x (2097152 float4s). blocks [8192,11264): Wq|Wk|Wv.
__global__ __launch_bounds__(256) void cast_all_kernel(const float* __restrict__ x,
                                                       const float* __restrict__ Wq,
                                                       const float* __restrict__ Wk,
                                                       const float* __restrict__ Wv,
                                                       u16* __restrict__ xb,
                                                       u16* __restrict__ Wb) {
  int b = blockIdx.x;
  if (b < 8192) {
    const int i = b * 256 + threadIdx.x;
    float4 v = reinterpret_cast<const float4*>(x)[i];
    reinterpret_cast<ushort4*>(xb)[i] =
        make_ushort4(f2b(v.x), f2b(v.y), f2b(v.z), f2b(v.w));
  } else {
    b -= 8192;
    const int w = b >> 10;
    const float* src = (w == 0) ? Wq : (w == 1) ? Wk : Wv;
    const int i = (b & 1023) * 256 + threadIdx.x;
    float4 v = reinterpret_cast<const float4*>(src)[i];
    reinterpret_cast<ushort4*>(Wb + (size_t)w * 1048576)[i] =
        make_ushort4(f2b(v.x), f2b(v.y), f2b(v.z), f2b(v.w));
  }
}

// ---------------- deep-prefetch 8-phase core (R4, validated) ----------------
// GEOM 0: BM=256,BN=256 (acc f32x4[32]); GEOM 1: BM=128,BN=256 (acc f32x4[16]).
// 8 waves: wr=wave>>2 (M), wc=wave&3 (N). BK=64, NT K-tiles. lda/ldb in BYTES.
// Stage stream: phase g issues S(g+6); steady wait vmcnt(8)/(6) at p1,p3 ends.
template <int GEOM, int NT>
__device__ __forceinline__ void core8(const char* __restrict__ Ab,
                                      const char* __restrict__ Bb, int lda, int ldb,
                                      char* smem, f32x4* acc) {
  constexpr int LDSBUF = GEOM ? 49152 : 65536;
  constexpr int BOFF = GEOM ? 16384 : 32768;
  constexpr int AHALF = GEOM ? 8192 : 16384;
  const int tid = threadIdx.x;
  const int wave = tid >> 6, lane = tid & 63;
  const int wr = wave >> 2, wc = wave & 3;
  const int fr = lane & 15, fg = lane >> 4;
  const int rd = (fr * 64 + fg * 16) ^ (((fr >> 3) & 1) << 5);
  const int li = (lane * 16) ^ ((lane >> 5) << 5);
  const int sr = li >> 6, sc2 = li & 63;

  auto STAGE = [&](int kt, int p) {
    const int isB = p & 1, s = p >> 1;
    char* lds = smem + (kt & 1) * LDSBUF + (isB ? BOFF + s * 16384 : s * AHALF);
    const char* gb = isB ? Bb : Ab;
    const int ldx = isB ? ldb : lda;
    const int colOff = kt * 128 + s * 64 + sc2;
    __builtin_amdgcn_global_load_lds(
        (const __attribute__((address_space(1))) void*)(gb + (size_t)(wave * 16 + sr) * ldx + colOff),
        (__attribute__((address_space(3))) void*)(lds + wave * 1024), 16, 0, 0);
    if (isB || GEOM == 0)
      __builtin_amdgcn_global_load_lds(
          (const __attribute__((address_space(1))) void*)(gb + (size_t)((8 + wave) * 16 + sr) * ldx + colOff),
          (__attribute__((address_space(3))) void*)(lds + 8192 + wave * 1024), 16, 0, 0);
  };

  // prologue: S(0..5) = tile0 all 4 halves + tile1 halves 0,1
#pragma unroll
  for (int p = 0; p < 4; ++p) STAGE(0, p);
  STAGE(1, 0);
  STAGE(1, 1);
  if constexpr (GEOM == 0) asm volatile("s_waitcnt vmcnt(8)" ::: "memory");
  else asm volatile("s_waitcnt vmcnt(6)" ::: "memory");
  __builtin_amdgcn_s_barrier();
  __builtin_amdgcn_sched_barrier(0);

  bf16x8 keep[4];  // GEOM0: B frags held across j; GEOM1: A frags held across j
  for (int kt = 0; kt < NT; ++kt) {
    const char* bufA = smem + (kt & 1) * LDSBUF;
    const char* bufB = bufA + BOFF;
#pragma unroll
    for (int p = 0; p < 4; ++p) {
      const int s = p >> 1, j = p & 1;
      if constexpr (GEOM == 0) {
        bf16x8 afr[4];
        if (j == 0)
#pragma unroll
          for (int n = 0; n < 4; ++n)
            keep[n] = *reinterpret_cast<const bf16x8*>(bufB + s * 16384 + (wc * 4 + n) * 1024 + rd);
#pragma unroll
        for (int m = 0; m < 4; ++m)
          afr[m] = *reinterpret_cast<const bf16x8*>(bufA + s * 16384 + (wr * 8 + j * 4 + m) * 1024 + rd);
        if (p < 2) { if (kt + 1 < NT) STAGE(kt + 1, p + 2); }
        else       { if (kt + 2 < NT) STAGE(kt + 2, p - 2); }
        __builtin_amdgcn_s_barrier();
        __builtin_amdgcn_sched_barrier(0);
        __builtin_amdgcn_s_setprio(1);
#pragma unroll
        for (int m = 0; m < 4; ++m)
#pragma unroll
          for (int n = 0; n < 4; ++n)
            acc[(j * 4 + m) * 4 + n] = __builtin_amdgcn_mfma_f32_16x16x32_bf16(
                afr[m], keep[n], acc[(j * 4 + m) * 4 + n], 0, 0, 0);
        __builtin_amdgcn_s_setprio(0);
      } else {
        bf16x8 bfr[2];
        if (j == 0)
#pragma unroll
          for (int m = 0; m < 4; ++m)
            keep[m] = *reinterpret_cast<const bf16x8*>(bufA + s * AHALF + (wr * 4 + m) * 1024 + rd);
#pragma unroll
        for (int nn = 0; nn < 2; ++nn)
          bfr[nn] = *reinterpret_cast<const bf16x8*>(bufB + s * 16384 + (wc * 4 + j * 2 + nn) * 1024 + rd);
        if (p < 2) { if (kt + 1 < NT) STAGE(kt + 1, p + 2); }
        else       { if (kt + 2 < NT) STAGE(kt + 2, p - 2); }
        __builtin_amdgcn_s_barrier();
        __builtin_amdgcn_sched_barrier(0);
        __builtin_amdgcn_s_setprio(1);
#pragma unroll
        for (int m = 0; m < 4; ++m)
#pragma unroll
          for (int nn = 0; nn < 2; ++nn)
            acc[m * 4 + j * 2 + nn] = __builtin_amdgcn_mfma_f32_16x16x32_bf16(
                keep[m], bfr[nn], acc[m * 4 + j * 2 + nn], 0, 0, 0);
        __builtin_amdgcn_s_setprio(0);
      }
      if (p == 1) {
        if (kt < NT - 1) {
          if constexpr (GEOM == 0) asm volatile("s_waitcnt vmcnt(8)" ::: "memory");
          else asm volatile("s_waitcnt vmcnt(6)" ::: "memory");
        } else {
          asm volatile("s_waitcnt vmcnt(0)" ::: "memory");
        }
      } else if (p == 3) {
        if (kt < NT - 2) {
          if constexpr (GEOM == 0) asm volatile("s_waitcnt vmcnt(8)" ::: "memory");
          else asm volatile("s_waitcnt vmcnt(6)" ::: "memory");
        } else if (kt == NT - 2) {
          if constexpr (GEOM == 0) asm volatile("s_waitcnt vmcnt(4)" ::: "memory");
          else asm volatile("s_waitcnt vmcnt(3)" ::: "memory");
        }
      }
      __builtin_amdgcn_s_barrier();
      __builtin_amdgcn_sched_barrier(0);
    }
  }
}

// ---------------- QKV projection: GEOM1, 3 chained N-tiles per block ----------------
// grid (64,4): tileM = bx*128; block handles N-tiles by = byc*3 + t, t=0..2.
// Flat ft = t*16 + kt in [0,48); stage cadence identical to core8 GEOM1.
__global__ __launch_bounds__(512, 2) void proj8_kernel(
    const u16* __restrict__ A, const u16* __restrict__ Bm,
    const float* __restrict__ bq, const float* __restrict__ bk,
    const float* __restrict__ bvv, u16* __restrict__ QK, u16* __restrict__ Vt) {
  extern __shared__ char smem[];  // 2 x 49152
  constexpr int FT = 48;
  const int tid = threadIdx.x;
  const int wave = tid >> 6, lane = tid & 63;
  const int wr = wave >> 2, wc = wave & 3;
  const int fr = lane & 15, fg = lane >> 4;
  const int rd = (fr * 64 + fg * 16) ^ (((fr >> 3) & 1) << 5);
  const int li = (lane * 16) ^ ((lane >> 5) << 5);
  const int sr = li >> 6, sc2 = li & 63;
  const int tileM = blockIdx.x * 128;
  const int byc = blockIdx.y;
  const char* Ab = (const char*)A + (size_t)tileM * 2048;
  const char* Bbase = (const char*)Bm + (size_t)byc * 3 * 524288;  // 256*2048 per tile

  auto STAGE = [&](int ft, int p) {
    if (ft >= FT) return;
    const int t = ft >> 4, kt = ft & 15;
    const int isB = p & 1, s = p >> 1;
    char* lds = smem + (ft & 1) * 49152 + (isB ? 16384 + s * 16384 : s * 8192);
    const int colOff = kt * 128 + s * 64 + sc2;
    if (!isB) {
      __builtin_amdgcn_global_load_lds(
          (const __attribute__((address_space(1))) void*)(Ab + (size_t)(wave * 16 + sr) * 2048 + colOff),
          (__attribute__((address_space(3))) void*)(lds + wave * 1024), 16, 0, 0);
    } else {
      const char* Bb = Bbase + (size_t)t * 524288;
      __builtin_amdgcn_global_load_lds(
          (const __attribute__((address_space(1))) void*)(Bb + (size_t)(wave * 16 + sr) * 2048 + colOff),
          (__attribute__((address_space(3))) void*)(lds + wave * 1024), 16, 0, 0);
      __builtin_amdgcn_global_load_lds(
          (const __attribute__((address_space(1))) void*)(Bb + (size_t)((8 + wave) * 16 + sr) * 2048 + colOff),
          (__attribute__((address_space(3))) void*)(lds + 8192 + wave * 1024), 16, 0, 0);
    }
  };

  // prologue: S(0..5)
#pragma unroll
  for (int p = 0; p < 4; ++p) STAGE(0, p);
  STAGE(1, 0);
  STAGE(1, 1);
  asm volatile("s_waitcnt vmcnt(6)" ::: "memory");
  __builtin_amdgcn_s_barrier();
  __builtin_amdgcn_sched_barrier(0);

  f32x4 acc[16] = {};
  bf16x8 keep[4];

  for (int ft = 0; ft < FT; ++ft) {
    const char* bufA = smem + (ft & 1) * 49152;
    const char* bufB = bufA + 16384;
#pragma unroll
    for (int p = 0; p < 4; ++p) {
      const int s = p >> 1, j = p & 1;
      bf16x8 bfr[2];
      if (j == 0)
#pragma unroll
        for (int m = 0; m < 4; ++m)
          keep[m] = *reinterpret_cast<const bf16x8*>(bufA + s * 8192 + (wr * 4 + m) * 1024 + rd);
#pragma unroll
      for (int nn = 0; nn < 2; ++nn)
        bfr[nn] = *reinterpret_cast<const bf16x8*>(bufB + s * 16384 + (wc * 4 + j * 2 + nn) * 1024 + rd);
      if (p < 2) STAGE(ft + 1, p + 2);
      else STAGE(ft + 2, p - 2);
      __builtin_amdgcn_s_barrier();
      __builtin_amdgcn_sched_barrier(0);
      __builtin_amdgcn_s_setprio(1);
#pragma unroll
      for (int m = 0; m < 4; ++m)
#pragma unroll
        for (int nn = 0; nn < 2; ++nn)
          acc[m * 4 + j * 2 + nn] = __builtin_amdgcn_mfma_f32_16x16x32_bf16(
              keep[m], bfr[nn], acc[m * 4 + j * 2 + nn], 0, 0, 0);
      __builtin_amdgcn_s_setprio(0);
      // counted waits on the flat stream (epilogue stores also count toward
      // vmcnt -> post-seam waits are conservative but safe)
      if (p == 1) {
        if (ft < FT - 1) asm volatile("s_waitcnt vmcnt(6)" ::: "memory");
        else asm volatile("s_waitcnt vmcnt(0)" ::: "memory");
      } else if (p == 3) {
        if (ft < FT - 2) asm volatile("s_waitcnt vmcnt(6)" ::: "memory");
        else if (ft == FT - 2) asm volatile("s_waitcnt vmcnt(3)" ::: "memory");
      }
      __builtin_amdgcn_s_barrier();
      __builtin_amdgcn_sched_barrier(0);
    }
    if ((ft & 15) == 15) {
      // epilogue for chained tile t = ft>>4 ; by = byc*3 + t
      const int by = byc * 3 + (ft >> 4);
      const int tileN = by * 256;
      const int w = by >> 2;
      const float* bias = (w == 0) ? bq : (w == 1) ? bk : bvv;
      if (w < 2) {
        u16* O = QK + (size_t)w * 8388608;
#pragma unroll
        for (int mi = 0; mi < 4; ++mi) {
          const int r0 = tileM + wr * 64 + mi * 16 + fg * 4;
#pragma unroll
          for (int n = 0; n < 4; ++n) {
            const int cw = (tileN + wc * 64 + n * 16 + fr) & 1023;
            const float bi = bias[cw];
#pragma unroll
            for (int jj = 0; jj < 4; ++jj)
              O[(size_t)(r0 + jj) * 1024 + cw] = f2b(acc[mi * 4 + n][jj] + bi);
          }
        }
      } else {
#pragma unroll
        for (int mi = 0; mi < 4; ++mi) {
          const int r0 = tileM + wr * 64 + mi * 16 + fg * 4;
          const int b = r0 >> 11, s0 = r0 & 2047;
#pragma unroll
          for (int n = 0; n < 4; ++n) {
            const int cw = (tileN + wc * 64 + n * 16 + fr) & 1023;
            const float bi = bias[cw];
            ushort4 u = make_ushort4(f2b(acc[mi * 4 + n][0] + bi), f2b(acc[mi * 4 + n][1] + bi),
                                     f2b(acc[mi * 4 + n][2] + bi), f2b(acc[mi * 4 + n][3] + bi));
            *reinterpret_cast<ushort4*>(&Vt[(size_t)b * 2097152 + (size_t)cw * 2048 + s0]) = u;
          }
        }
      }
#pragma unroll
      for (int i = 0; i < 16; ++i) acc[i] = f32x4{};
    }
  }
}

// ---------------- sc: P~ = exp(Q K^T / 32) (bf16) + row-sum partials ----------------
__global__ __launch_bounds__(512, 2) void sc8_kernel(const u16* __restrict__ Qb,
                                                     const u16* __restrict__ Kb,
                                                     u16* __restrict__ P,
                                                     float* __restrict__ rowpart) {
  extern __shared__ char smem[];
  const int z = blockIdx.z;
  const int tileM = blockIdx.x * 256, tileN = blockIdx.y * 256;
  f32x4 acc[32] = {};
  core8<0, 16>((const char*)Qb + (size_t)z * 4194304 + (size_t)tileM * 2048,
               (const char*)Kb + (size_t)z * 4194304 + (size_t)tileN * 2048, 2048, 2048,
               smem, acc);
  const int tid = threadIdx.x;
  const int wave = tid >> 6, lane = tid & 63;
  const int wr = wave >> 2, wc = wave & 3, fr = lane & 15, fg = lane >> 4;
  float* rs = (float*)smem;  // [4][256]; safe: core8 ends with full barrier
  u16* Po = P + (size_t)z * 4194304 + (size_t)tileM * 2048 + tileN;
#pragma unroll
  for (int mi = 0; mi < 8; ++mi) {
#pragma unroll
    for (int jj = 0; jj < 4; ++jj) {
      const int rl = wr * 128 + mi * 16 + fg * 4 + jj;
      float part = 0.f;
#pragma unroll
      for (int n = 0; n < 4; ++n) {
        float e = __expf(acc[mi * 4 + n][jj] * 0.03125f);
        part += e;
        Po[(size_t)rl * 2048 + wc * 64 + n * 16 + fr] = f2b(e);
      }
      part += __shfl_xor(part, 1);
      part += __shfl_xor(part, 2);
      part += __shfl_xor(part, 4);
      part += __shfl_xor(part, 8);
      if (fr == 0) rs[wc * 256 + rl] = part;
    }
  }
  __syncthreads();
  if (tid < 256) {
    float s = rs[tid] + rs[256 + tid] + rs[512 + tid] + rs[768 + tid];
    rowpart[(size_t)blockIdx.y * 8192 + z * 2048 + tileM + tid] = s;
  }
}

// ---------------- pv: out = (P~ Vt^T) * rowinv (rowinv computed in-kernel) ----------------
__global__ __launch_bounds__(512, 2) void pv8_kernel(const u16* __restrict__ P,
                                                     const u16* __restrict__ Vt,
                                                     const float* __restrict__ rowpart,
                                                     float* __restrict__ out) {
  extern __shared__ char smem[];  // 98304 core + 512 rowinv
  const int z = blockIdx.z;
  const int tileM = blockIdx.x * 128, tileN = blockIdx.y * 256;
  float* rinv = (float*)(smem + 98304);
  const int tid = threadIdx.x;
  if (tid < 128) {
    float s = 0.f;
#pragma unroll
    for (int t = 0; t < 8; ++t) s += rowpart[t * 8192 + z * 2048 + tileM + tid];
    rinv[tid] = 1.0f / s;
  }
  // core8's first barrier orders the rinv write before epilogue reads.
  f32x4 acc[16] = {};
  core8<1, 32>((const char*)P + (size_t)z * 8388608 + (size_t)tileM * 4096,
               (const char*)Vt + (size_t)z * 4194304 + (size_t)tileN * 4096, 4096, 4096,
               smem, acc);
  const int wave = tid >> 6, lane = tid & 63;
  const int wr = wave >> 2, wc = wave & 3, fr = lane & 15, fg = lane >> 4;
  float* O = out + (size_t)z * 2097152;
#pragma unroll
  for (int mi = 0; mi < 4; ++mi) {
#pragma unroll
    for (int jj = 0; jj < 4; ++jj) {
      const int r = wr * 64 + mi * 16 + fg * 4 + jj;
      const float inv = rinv[r];
#pragma unroll
      for (int n = 0; n < 4; ++n)
        O[(size_t)(tileM + r) * 1024 + tileN + wc * 64 + n * 16 + fr] =
            acc[mi * 4 + n][jj] * inv;
    }
  }
}

extern "C" void kernel_launch(void* const* d_in, const int* in_sizes, int n_in,
                              void* d_out, int out_size, void* d_ws, size_t ws_size,
                              hipStream_t stream) {
  if (ws_size < ((size_t)72 << 20)) return;
  const float* x = (const float*)d_in[0];
  const float* Wq = (const float*)d_in[1];
  const float* bq = (const float*)d_in[2];
  const float* Wk = (const float*)d_in[3];
  const float* bk = (const float*)d_in[4];
  const float* Wv = (const float*)d_in[5];
  const float* bv = (const float*)d_in[6];
  char* ws = (char*)d_ws;
  u16* xb = (u16*)(ws);                       // [0,16M); later P~ [4][2048][2048]
  u16* Pb = (u16*)(ws);
  u16* Qb = (u16*)(ws + ((size_t)16 << 20));
  u16* Kb = (u16*)(ws + ((size_t)32 << 20));
  u16* Vt = (u16*)(ws + ((size_t)48 << 20));
  u16* Wb = (u16*)(ws + ((size_t)64 << 20));
  float* rowpart = (float*)(ws + ((size_t)70 << 20));  // 256 KiB
  float* out = (float*)d_out;

  (void)hipFuncSetAttribute((const void*)proj8_kernel,
                            hipFuncAttributeMaxDynamicSharedMemorySize, 98304);
  (void)hipFuncSetAttribute((const void*)sc8_kernel,
                            hipFuncAttributeMaxDynamicSharedMemorySize, 131072);
  (void)hipFuncSetAttribute((const void*)pv8_kernel,
                            hipFuncAttributeMaxDynamicSharedMemorySize, 98816);

  cast_all_kernel<<<11264, 256, 0, stream>>>(x, Wq, Wk, Wv, xb, Wb);

  proj8_kernel<<<dim3(64, 4), 512, 98304, stream>>>(xb, Wb, bq, bk, bv, Qb, Vt);

  sc8_kernel<<<dim3(8, 8, 4), 512, 131072, stream>>>(Qb, Kb, Pb, rowpart);
  pv8_kernel<<<dim3(16, 4, 4), 512, 98816, stream>>>(Pb, Vt, rowpart, out);
}

// Round 8
// 155.484 us; speedup vs baseline: 1.0114x; 1.0114x over previous
//
#include <hip/hip_runtime.h>

// SelfAttention: B=4, S=2048, D=1024, fp32 in/out. bf16 MFMA, fp32 accum.
// R7: merged-phase core2 (2 phases per K-tile; GEOM0 32 MFMA/phase, GEOM1 16).
// Rationale: per-phase fixed cost (~100+ cyc: 2 barriers + waits at 1 block/CU)
// is the measured tax; halving phase count halves it per MFMA. R6 chaining
// reverted (regressed). proj back to R5 exact-fill grid (64,12).
//   proj: 128x256 GEOM1, grid (64,12) = 768 = 3 exact rounds
//   sc:   256x256 GEOM0, grid (8,8,4) = 256, P~=exp(QK^T/32)+rowsums
//   pv:   128x256 GEOM1, grid (16,4,4) = 256, * 1/rowsum (in-kernel rsum)
// ws layout (MiB):
//   [0,16)   x_bf16 (proj) -> P~ bf16 [4][2048][2048]
//   [16,32)  Q bf16   [32,48) K bf16   [48,64) Vt bf16 [4][1024][2048]
//   [64,70)  Wq|Wk|Wv bf16
//   [70,+256K) rowpart fp32 [8][4][2048]

typedef __bf16 bf16x8 __attribute__((ext_vector_type(8)));
typedef float f32x4 __attribute__((ext_vector_type(4)));
typedef unsigned short u16;

__device__ __forceinline__ u16 f2b(float f) {
  union { float f; unsigned u; } a; a.f = f;
  unsigned r = a.u + 0x7fffu + ((a.u >> 16) & 1u);  // RNE
  return (u16)(r >> 16);
}

// blocks [0,8192): x (2097152 float4s). blocks [8192,11264): Wq|Wk|Wv.
__global__ __launch_bounds__(256) void cast_all_kernel(const float* __restrict__ x,
                                                       const float* __restrict__ Wq,
                                                       const float* __restrict__ Wk,
                                                       const float* __restrict__ Wv,
                                                       u16* __restrict__ xb,
                                                       u16* __restrict__ Wb) {
  int b = blockIdx.x;
  if (b < 8192) {
    const int i = b * 256 + threadIdx.x;
    float4 v = reinterpret_cast<const float4*>(x)[i];
    reinterpret_cast<ushort4*>(xb)[i] =
        make_ushort4(f2b(v.x), f2b(v.y), f2b(v.z), f2b(v.w));
  } else {
    b -= 8192;
    const int w = b >> 10;
    const float* src = (w == 0) ? Wq : (w == 1) ? Wk : Wv;
    const int i = (b & 1023) * 256 + threadIdx.x;
    float4 v = reinterpret_cast<const float4*>(src)[i];
    reinterpret_cast<ushort4*>(Wb + (size_t)w * 1048576)[i] =
        make_ushort4(f2b(v.x), f2b(v.y), f2b(v.z), f2b(v.w));
  }
}

// ---------------- merged-phase double-buffered core (R7) ----------------
// GEOM 0: BM=256,BN=256, acc f32x4[32]; GEOM 1: BM=128,BN=256, acc f32x4[16].
// 8 waves: wr=wave>>2 (M), wc=wave&3 (N). BK=64, NT K-tiles. lda/ldb in BYTES.
// 2 phases per K-tile (s = K-half). Phase: {ds_read A+B frags of half s;
// STAGE half s of kt+1; barrier; MFMA cluster; counted vmcnt; barrier}.
// vmcnt invariant: steady outstanding = 2 stages (8/6 loads), need oldest ->
// vmcnt(4) GEOM0 / vmcnt(3) GEOM1; tail kt=NT-1: s0 -> vmcnt(0), s1 -> none.
template <int GEOM, int NT>
__device__ __forceinline__ void core2(const char* __restrict__ Ab,
                                      const char* __restrict__ Bb, int lda, int ldb,
                                      char* smem, f32x4* acc) {
  constexpr int LDSBUF = GEOM ? 49152 : 65536;
  constexpr int BOFF = GEOM ? 16384 : 32768;
  constexpr int AHALF = GEOM ? 8192 : 16384;
  constexpr int NA = GEOM ? 4 : 8;  // A fragments (16-row subtiles) per phase
  const int tid = threadIdx.x;
  const int wave = tid >> 6, lane = tid & 63;
  const int wr = wave >> 2, wc = wave & 3;
  const int fr = lane & 15, fg = lane >> 4;
  const int rd = (fr * 64 + fg * 16) ^ (((fr >> 3) & 1) << 5);
  const int li = (lane * 16) ^ ((lane >> 5) << 5);
  const int sr = li >> 6, sc2 = li & 63;

  auto STAGE = [&](int kt, int s) {  // A-half s + B-half s of tile kt
    char* base = smem + (kt & 1) * LDSBUF;
    const int colOff = kt * 128 + s * 64 + sc2;
    char* ldsA = base + s * AHALF;
    __builtin_amdgcn_global_load_lds(
        (const __attribute__((address_space(1))) void*)(Ab + (size_t)(wave * 16 + sr) * lda + colOff),
        (__attribute__((address_space(3))) void*)(ldsA + wave * 1024), 16, 0, 0);
    if constexpr (GEOM == 0)
      __builtin_amdgcn_global_load_lds(
          (const __attribute__((address_space(1))) void*)(Ab + (size_t)((8 + wave) * 16 + sr) * lda + colOff),
          (__attribute__((address_space(3))) void*)(ldsA + 8192 + wave * 1024), 16, 0, 0);
    char* ldsB = base + BOFF + s * 16384;
    __builtin_amdgcn_global_load_lds(
        (const __attribute__((address_space(1))) void*)(Bb + (size_t)(wave * 16 + sr) * ldb + colOff),
        (__attribute__((address_space(3))) void*)(ldsB + wave * 1024), 16, 0, 0);
    __builtin_amdgcn_global_load_lds(
        (const __attribute__((address_space(1))) void*)(Bb + (size_t)((8 + wave) * 16 + sr) * ldb + colOff),
        (__attribute__((address_space(3))) void*)(ldsB + 8192 + wave * 1024), 16, 0, 0);
  };

  // prologue: both halves of tile 0; land half 0, keep half 1 in flight
  STAGE(0, 0);
  STAGE(0, 1);
  if constexpr (GEOM == 0) asm volatile("s_waitcnt vmcnt(4)" ::: "memory");
  else asm volatile("s_waitcnt vmcnt(3)" ::: "memory");
  __builtin_amdgcn_s_barrier();
  __builtin_amdgcn_sched_barrier(0);

  for (int kt = 0; kt < NT; ++kt) {
    const char* bufA = smem + (kt & 1) * LDSBUF;
    const char* bufB = bufA + BOFF;
#pragma unroll
    for (int s = 0; s < 2; ++s) {
      bf16x8 afr[NA], bfr[4];
#pragma unroll
      for (int m = 0; m < NA; ++m)
        afr[m] = *reinterpret_cast<const bf16x8*>(bufA + s * AHALF + (wr * NA + m) * 1024 + rd);
#pragma unroll
      for (int n = 0; n < 4; ++n)
        bfr[n] = *reinterpret_cast<const bf16x8*>(bufB + s * 16384 + (wc * 4 + n) * 1024 + rd);
      if (kt + 1 < NT) STAGE(kt + 1, s);
      __builtin_amdgcn_s_barrier();
      __builtin_amdgcn_sched_barrier(0);
      __builtin_amdgcn_s_setprio(1);
#pragma unroll
      for (int m = 0; m < NA; ++m)
#pragma unroll
        for (int n = 0; n < 4; ++n)
          acc[m * 4 + n] = __builtin_amdgcn_mfma_f32_16x16x32_bf16(
              afr[m], bfr[n], acc[m * 4 + n], 0, 0, 0);
      __builtin_amdgcn_s_setprio(0);
      if (kt < NT - 1) {
        if constexpr (GEOM == 0) asm volatile("s_waitcnt vmcnt(4)" ::: "memory");
        else asm volatile("s_waitcnt vmcnt(3)" ::: "memory");
      } else if (s == 0) {
        asm volatile("s_waitcnt vmcnt(0)" ::: "memory");
      }
      __builtin_amdgcn_s_barrier();
      __builtin_amdgcn_sched_barrier(0);
    }
  }
}

// ---------------- QKV projection: GEOM1, grid (64,12) = 768 = 3 exact rounds ----------------
// A = xb [8192][1024], B = Wb [3072][1024]. w = by>>2: 0/1 -> Q/K; 2 -> Vt transposed.
__global__ __launch_bounds__(512, 2) void proj8_kernel(
    const u16* __restrict__ A, const u16* __restrict__ Bm,
    const float* __restrict__ bq, const float* __restrict__ bk,
    const float* __restrict__ bvv, u16* __restrict__ QK, u16* __restrict__ Vt) {
  extern __shared__ char smem[];
  const int tileM = blockIdx.x * 128, tileN = blockIdx.y * 256;
  f32x4 acc[16] = {};
  core2<1, 16>((const char*)A + (size_t)tileM * 2048,
               (const char*)Bm + (size_t)tileN * 2048, 2048, 2048, smem, acc);
  const int tid = threadIdx.x;
  const int wave = tid >> 6, lane = tid & 63;
  const int wr = wave >> 2, wc = wave & 3, fr = lane & 15, fg = lane >> 4;
  const int w = blockIdx.y >> 2;  // weight id (256-col tiles never straddle weights)
  const float* bias = (w == 0) ? bq : (w == 1) ? bk : bvv;
  if (w < 2) {
    u16* O = QK + (size_t)w * 8388608;
#pragma unroll
    for (int mi = 0; mi < 4; ++mi) {
      const int r0 = tileM + wr * 64 + mi * 16 + fg * 4;
#pragma unroll
      for (int n = 0; n < 4; ++n) {
        const int cw = (tileN + wc * 64 + n * 16 + fr) & 1023;
        const float bi = bias[cw];
#pragma unroll
        for (int jj = 0; jj < 4; ++jj)
          O[(size_t)(r0 + jj) * 1024 + cw] = f2b(acc[mi * 4 + n][jj] + bi);
      }
    }
  } else {
#pragma unroll
    for (int mi = 0; mi < 4; ++mi) {
      const int r0 = tileM + wr * 64 + mi * 16 + fg * 4;
      const int b = r0 >> 11, s0 = r0 & 2047;  // rows r0..r0+3 never straddle a batch
#pragma unroll
      for (int n = 0; n < 4; ++n) {
        const int cw = (tileN + wc * 64 + n * 16 + fr) & 1023;
        const float bi = bias[cw];
        ushort4 u = make_ushort4(f2b(acc[mi * 4 + n][0] + bi), f2b(acc[mi * 4 + n][1] + bi),
                                 f2b(acc[mi * 4 + n][2] + bi), f2b(acc[mi * 4 + n][3] + bi));
        *reinterpret_cast<ushort4*>(&Vt[(size_t)b * 2097152 + (size_t)cw * 2048 + s0]) = u;
      }
    }
  }
}

// ---------------- sc: P~ = exp(Q K^T / 32) (bf16) + row-sum partials ----------------
__global__ __launch_bounds__(512, 2) void sc8_kernel(const u16* __restrict__ Qb,
                                                     const u16* __restrict__ Kb,
                                                     u16* __restrict__ P,
                                                     float* __restrict__ rowpart) {
  extern __shared__ char smem[];
  const int z = blockIdx.z;
  const int tileM = blockIdx.x * 256, tileN = blockIdx.y * 256;
  f32x4 acc[32] = {};
  core2<0, 16>((const char*)Qb + (size_t)z * 4194304 + (size_t)tileM * 2048,
               (const char*)Kb + (size_t)z * 4194304 + (size_t)tileN * 2048, 2048, 2048,
               smem, acc);
  const int tid = threadIdx.x;
  const int wave = tid >> 6, lane = tid & 63;
  const int wr = wave >> 2, wc = wave & 3, fr = lane & 15, fg = lane >> 4;
  float* rs = (float*)smem;  // [4][256]; safe: core2 ends with full barrier
  u16* Po = P + (size_t)z * 4194304 + (size_t)tileM * 2048 + tileN;
#pragma unroll
  for (int mi = 0; mi < 8; ++mi) {
#pragma unroll
    for (int jj = 0; jj < 4; ++jj) {
      const int rl = wr * 128 + mi * 16 + fg * 4 + jj;
      float part = 0.f;
#pragma unroll
      for (int n = 0; n < 4; ++n) {
        float e = __expf(acc[mi * 4 + n][jj] * 0.03125f);
        part += e;
        Po[(size_t)rl * 2048 + wc * 64 + n * 16 + fr] = f2b(e);
      }
      part += __shfl_xor(part, 1);
      part += __shfl_xor(part, 2);
      part += __shfl_xor(part, 4);
      part += __shfl_xor(part, 8);
      if (fr == 0) rs[wc * 256 + rl] = part;
    }
  }
  __syncthreads();
  if (tid < 256) {
    float s = rs[tid] + rs[256 + tid] + rs[512 + tid] + rs[768 + tid];
    rowpart[(size_t)blockIdx.y * 8192 + z * 2048 + tileM + tid] = s;
  }
}

// ---------------- pv: out = (P~ Vt^T) * rowinv (rowinv computed in-kernel) ----------------
__global__ __launch_bounds__(512, 2) void pv8_kernel(const u16* __restrict__ P,
                                                     const u16* __restrict__ Vt,
                                                     const float* __restrict__ rowpart,
                                                     float* __restrict__ out) {
  extern __shared__ char smem[];  // 98304 core + 512 rowinv
  const int z = blockIdx.z;
  const int tileM = blockIdx.x * 128, tileN = blockIdx.y * 256;
  float* rinv = (float*)(smem + 98304);
  const int tid = threadIdx.x;
  if (tid < 128) {
    float s = 0.f;
#pragma unroll
    for (int t = 0; t < 8; ++t) s += rowpart[t * 8192 + z * 2048 + tileM + tid];
    rinv[tid] = 1.0f / s;
  }
  __builtin_amdgcn_sched_barrier(0);  // pin rinv loads/stores before staging
  // core2's first barrier orders the rinv write before epilogue reads.
  f32x4 acc[16] = {};
  core2<1, 32>((const char*)P + (size_t)z * 8388608 + (size_t)tileM * 4096,
               (const char*)Vt + (size_t)z * 4194304 + (size_t)tileN * 4096, 4096, 4096,
               smem, acc);
  const int wave = tid >> 6, lane = tid & 63;
  const int wr = wave >> 2, wc = wave & 3, fr = lane & 15, fg = lane >> 4;
  float* O = out + (size_t)z * 2097152;
#pragma unroll
  for (int mi = 0; mi < 4; ++mi) {
#pragma unroll
    for (int jj = 0; jj < 4; ++jj) {
      const int r = wr * 64 + mi * 16 + fg * 4 + jj;
      const float inv = rinv[r];
#pragma unroll
      for (int n = 0; n < 4; ++n)
        O[(size_t)(tileM + r) * 1024 + tileN + wc * 64 + n * 16 + fr] =
            acc[mi * 4 + n][jj] * inv;
    }
  }
}

extern "C" void kernel_launch(void* const* d_in, const int* in_sizes, int n_in,
                              void* d_out, int out_size, void* d_ws, size_t ws_size,
                              hipStream_t stream) {
  if (ws_size < ((size_t)72 << 20)) return;
  const float* x = (const float*)d_in[0];
  const float* Wq = (const float*)d_in[1];
  const float* bq = (const float*)d_in[2];
  const float* Wk = (const float*)d_in[3];
  const float* bk = (const float*)d_in[4];
  const float* Wv = (const float*)d_in[5];
  const float* bv = (const float*)d_in[6];
  char* ws = (char*)d_ws;
  u16* xb = (u16*)(ws);                       // [0,16M); later P~ [4][2048][2048]
  u16* Pb = (u16*)(ws);
  u16* Qb = (u16*)(ws + ((size_t)16 << 20));
  u16* Kb = (u16*)(ws + ((size_t)32 << 20));
  u16* Vt = (u16*)(ws + ((size_t)48 << 20));
  u16* Wb = (u16*)(ws + ((size_t)64 << 20));
  float* rowpart = (float*)(ws + ((size_t)70 << 20));  // 256 KiB
  float* out = (float*)d_out;

  (void)hipFuncSetAttribute((const void*)proj8_kernel,
                            hipFuncAttributeMaxDynamicSharedMemorySize, 98304);
  (void)hipFuncSetAttribute((const void*)sc8_kernel,
                            hipFuncAttributeMaxDynamicSharedMemorySize, 131072);
  (void)hipFuncSetAttribute((const void*)pv8_kernel,
                            hipFuncAttributeMaxDynamicSharedMemorySize, 98816);

  cast_all_kernel<<<11264, 256, 0, stream>>>(x, Wq, Wk, Wv, xb, Wb);

  proj8_kernel<<<dim3(64, 12), 512, 98304, stream>>>(xb, Wb, bq, bk, bv, Qb, Vt);

  sc8_kernel<<<dim3(8, 8, 4), 512, 131072, stream>>>(Qb, Kb, Pb, rowpart);
  pv8_kernel<<<dim3(16, 4, 4), 512, 98816, stream>>>(Pb, Vt, rowpart, out);
}